// Round 24
// baseline (149.343 us; speedup 1.0000x reference)
//
#include <hip/hip_runtime.h>
#include <hip/hip_fp16.h>

#define N_NODES 50000
#define N_EDGES 800000
#define D_FEAT 128
#define HEADS 8
#define UNITS 32
#define HU (HEADS * UNITS) /* 256 */
#define LEAKY 0.2f
#define EPSV 1e-7f
#define NBLK 196 /* ceil(50000/256) */

typedef _Float16 half8 __attribute__((ext_vector_type(8)));
typedef float f32x4 __attribute__((ext_vector_type(4)));

struct h4pk { __half2 a, b; }; // 4 fp16 channels = 8 bytes

// ---- W -> W^T fp16 + zero counts + zero gtotal ----
#define WBLK 128 /* 128*256 = 32768 = D_FEAT*HU */
__global__ __launch_bounds__(256) void k_wt(const float* __restrict__ W,
                                            __half* __restrict__ Wt,
                                            int* __restrict__ counts,
                                            int* __restrict__ gtotal) {
    const int i = blockIdx.x * 256 + threadIdx.x; // i = n*128 + k
    const int n = i >> 7, k = i & 127;
    Wt[i] = __float2half(W[k * HU + n]);          // Wt[n][k] = W[k][n]
    for (int j = i; j < N_NODES; j += WBLK * 256) counts[j] = 0;
    if (i == 0) gtotal[0] = 0;
}

// ---- BIG: gemm blocks [0,GB) + count blocks [GB,GB+CB) ----
#define GB 1563 /* ceil(50000/32) gemm blocks */
#define CB 3125 /* 800000/256 count blocks, 4 edges/thread */
__global__ __launch_bounds__(64, 1) void k_big(const float* __restrict__ x,
                                               const __half* __restrict__ Wt,
                                               const float* __restrict__ ka1,
                                               const int* __restrict__ edges,
                                               int* __restrict__ counts,
                                               int* __restrict__ rank,
                                               __half* __restrict__ h,
                                               float* __restrict__ f) {
    const int l = threadIdx.x;
    if (blockIdx.x >= GB) {
        const int base = (blockIdx.x - GB) * 256;
#pragma unroll
        for (int j = 0; j < 4; ++j) {
            const int e = base + j * 64 + l;
            if (e < N_EDGES) {
                const int tgt = edges[2 * e + 1];
                rank[e] = atomicAdd(&counts[tgt], 1);
            }
        }
        return;
    }
    const int row16 = l & 15, kg = l >> 4;
    const int rbase = blockIdx.x * 32;

    half8 a0[4], a1[4];
    const int r0 = min(rbase + row16, N_NODES - 1);
    const int r1 = min(rbase + 16 + row16, N_NODES - 1);
    const float* xp0 = x + (size_t)r0 * D_FEAT + kg * 8;
    const float* xp1 = x + (size_t)r1 * D_FEAT + kg * 8;
#pragma unroll
    for (int ks = 0; ks < 4; ++ks) {
        const float4 u0 = *reinterpret_cast<const float4*>(xp0 + ks * 32);
        const float4 v0 = *reinterpret_cast<const float4*>(xp0 + ks * 32 + 4);
        const float4 u1 = *reinterpret_cast<const float4*>(xp1 + ks * 32);
        const float4 v1 = *reinterpret_cast<const float4*>(xp1 + ks * 32 + 4);
        half8 t0, t1;
        t0[0] = (_Float16)u0.x; t0[1] = (_Float16)u0.y; t0[2] = (_Float16)u0.z; t0[3] = (_Float16)u0.w;
        t0[4] = (_Float16)v0.x; t0[5] = (_Float16)v0.y; t0[6] = (_Float16)v0.z; t0[7] = (_Float16)v0.w;
        t1[0] = (_Float16)u1.x; t1[1] = (_Float16)u1.y; t1[2] = (_Float16)u1.z; t1[3] = (_Float16)u1.w;
        t1[4] = (_Float16)v1.x; t1[5] = (_Float16)v1.y; t1[6] = (_Float16)v1.z; t1[7] = (_Float16)v1.w;
        a0[ks] = t0; a1[ks] = t1;
    }

    f32x4 acc0[16], acc1[16];
#pragma unroll
    for (int ct = 0; ct < 16; ++ct) {
        acc0[ct] = (f32x4){0.f, 0.f, 0.f, 0.f};
        acc1[ct] = (f32x4){0.f, 0.f, 0.f, 0.f};
    }

#pragma unroll
    for (int ct = 0; ct < 16; ++ct) {
        const __half* wp = Wt + (ct * 16 + row16) * D_FEAT + kg * 8;
#pragma unroll
        for (int ks = 0; ks < 4; ++ks) {
            const half8 bf = *reinterpret_cast<const half8*>(wp + ks * 32);
            acc0[ct] = __builtin_amdgcn_mfma_f32_16x16x32_f16(a0[ks], bf, acc0[ct], 0, 0, 0);
            acc1[ct] = __builtin_amdgcn_mfma_f32_16x16x32_f16(a1[ks], bf, acc1[ct], 0, 0, 0);
        }
    }

    // register-direct epilogue: scalar h stores from acc + shuffle-f
#pragma unroll
    for (int tile = 0; tile < 2; ++tile) {
        const int rb2 = rbase + tile * 16;
#pragma unroll
        for (int ct = 0; ct < 16; ++ct) {
            const int col = ct * 16 + row16;
            const f32x4 av = tile ? acc1[ct] : acc0[ct];
#pragma unroll
            for (int r = 0; r < 4; ++r) {
                const int hr = rb2 + kg * 4 + r;
                if (hr < N_NODES)
                    h[(size_t)hr * HU + col] = __float2half(av[r]);
            }
        }
#pragma unroll
        for (int hd = 0; hd < 8; ++hd) {
            const float ka = ka1[hd * 32 + row16];
            const float kb = ka1[hd * 32 + 16 + row16];
            const f32x4 ae = tile ? acc1[2 * hd] : acc0[2 * hd];
            const f32x4 ao = tile ? acc1[2 * hd + 1] : acc0[2 * hd + 1];
#pragma unroll
            for (int r = 0; r < 4; ++r) {
                float v = ae[r] * ka + ao[r] * kb;
                v += __shfl_xor(v, 1);
                v += __shfl_xor(v, 2);
                v += __shfl_xor(v, 4);
                v += __shfl_xor(v, 8);
                if (row16 == 0) {
                    const int hr = rb2 + kg * 4 + r;
                    if (hr < N_NODES) f[(size_t)hr * HEADS + hd] = v;
                }
            }
        }
    }
}

// ---- offs via wave-scan + one atomic per wave + g-gather ----
__global__ __launch_bounds__(256) void k_offs(const int* __restrict__ counts,
                                              const int* __restrict__ edges,
                                              const float* __restrict__ f,
                                              int* __restrict__ offs,
                                              float* __restrict__ g,
                                              int* __restrict__ gtotal) {
    const int i = blockIdx.x * 256 + threadIdx.x;
    const int lane = threadIdx.x & 63;
    const int v = (i < N_NODES) ? counts[i] : 0;
    int inc = v;
#pragma unroll
    for (int o = 1; o < 64; o <<= 1) {
        const int u = __shfl_up(inc, o);
        if (lane >= o) inc += u;
    }
    const int wsum = __shfl(inc, 63);
    int base = 0;
    if (lane == 63 && wsum > 0) base = atomicAdd(gtotal, wsum);
    base = __shfl(base, 63);
    if (i < N_NODES) {
        offs[i] = base + inc - v; // exclusive within wave + wave base
        const int t2 = edges[2 * i + 1]; // quirk: f_s = f_t[sources]
        const float4 A = *reinterpret_cast<const float4*>(f + (size_t)t2 * HEADS);
        const float4 B = *reinterpret_cast<const float4*>(f + (size_t)t2 * HEADS + 4);
        *reinterpret_cast<float4*>(g + (size_t)i * HEADS) = A;
        *reinterpret_cast<float4*>(g + (size_t)i * HEADS + 4) = B;
    }
}

// ---- atomic-free single-pass CSR fill ----
#define EBLK 3125 /* 3125*256 = 800,000 */
__global__ __launch_bounds__(256) void k_fill(const int* __restrict__ edges,
                                              const int* __restrict__ offs,
                                              const int* __restrict__ rank,
                                              int* __restrict__ elist) {
    const int e = blockIdx.x * 256 + threadIdx.x;
    if (e >= N_EDGES) return;
    const int2 st = reinterpret_cast<const int2*>(edges)[e];
    elist[offs[st.y] + rank[e]] = st.x;
}

// ---- single sweep, no-max softmax + weighted gather; 16-deep pipeline ----
__global__ __launch_bounds__(256) void k_out(const __half* __restrict__ h,
                                             const int* __restrict__ elist,
                                             const float* __restrict__ f,
                                             const float* __restrict__ g,
                                             const int* __restrict__ offs, // segment START
                                             const int* __restrict__ counts,
                                             const float* __restrict__ bias,
                                             float* __restrict__ out) {
    const int n = blockIdx.x * 4 + (threadIdx.x >> 6);
    if (n >= N_NODES) return;
    const int lane = threadIdx.x & 63;
    const int head = lane >> 3;
    const int c4 = lane * 4;
    const int start = offs[n];
    const int end = start + counts[n];
    const float fn = f[(size_t)n * HEADS + head];

    float d = 0.f;
    float4 acc = make_float4(0.f, 0.f, 0.f, 0.f);

    int p = start;
    // 16-deep batch: 16 elist + 16 g + 16 h loads in flight per wave
    for (; p + 16 <= end; p += 16) {
        int ss[16];
#pragma unroll
        for (int j = 0; j < 16; ++j) ss[j] = elist[p + j];
        float gz[16];
#pragma unroll
        for (int j = 0; j < 16; ++j) gz[j] = g[(size_t)ss[j] * HEADS + head];
        h4pk hv[16];
#pragma unroll
        for (int j = 0; j < 16; ++j) hv[j] = *reinterpret_cast<const h4pk*>(h + (size_t)ss[j] * HU + c4);
#pragma unroll
        for (int j = 0; j < 16; ++j) {
            float z = fn + gz[j];
            z = (z > 0.f) ? z : LEAKY * z;
            const float w = __expf(z);
            d += w;
            const float2 fa = __half22float2(hv[j].a);
            const float2 fb = __half22float2(hv[j].b);
            acc.x += w * fa.x; acc.y += w * fa.y; acc.z += w * fb.x; acc.w += w * fb.y;
        }
    }
    for (; p + 8 <= end; p += 8) {
        int ss[8];
#pragma unroll
        for (int j = 0; j < 8; ++j) ss[j] = elist[p + j];
        float gz[8];
#pragma unroll
        for (int j = 0; j < 8; ++j) gz[j] = g[(size_t)ss[j] * HEADS + head];
        h4pk hv[8];
#pragma unroll
        for (int j = 0; j < 8; ++j) hv[j] = *reinterpret_cast<const h4pk*>(h + (size_t)ss[j] * HU + c4);
#pragma unroll
        for (int j = 0; j < 8; ++j) {
            float z = fn + gz[j];
            z = (z > 0.f) ? z : LEAKY * z;
            const float w = __expf(z);
            d += w;
            const float2 fa = __half22float2(hv[j].a);
            const float2 fb = __half22float2(hv[j].b);
            acc.x += w * fa.x; acc.y += w * fa.y; acc.z += w * fb.x; acc.w += w * fb.y;
        }
    }
    for (; p + 4 <= end; p += 4) {
        int ss[4];
#pragma unroll
        for (int j = 0; j < 4; ++j) ss[j] = elist[p + j];
        float gz[4];
#pragma unroll
        for (int j = 0; j < 4; ++j) gz[j] = g[(size_t)ss[j] * HEADS + head];
        h4pk hv[4];
#pragma unroll
        for (int j = 0; j < 4; ++j) hv[j] = *reinterpret_cast<const h4pk*>(h + (size_t)ss[j] * HU + c4);
#pragma unroll
        for (int j = 0; j < 4; ++j) {
            float z = fn + gz[j];
            z = (z > 0.f) ? z : LEAKY * z;
            const float w = __expf(z);
            d += w;
            const float2 fa = __half22float2(hv[j].a);
            const float2 fb = __half22float2(hv[j].b);
            acc.x += w * fa.x; acc.y += w * fa.y; acc.z += w * fb.x; acc.w += w * fb.y;
        }
    }
    for (; p < end; ++p) {
        const int s = elist[p];
        float z = fn + g[(size_t)s * HEADS + head];
        z = (z > 0.f) ? z : LEAKY * z;
        const float w = __expf(z);
        const h4pk hv = *reinterpret_cast<const h4pk*>(h + (size_t)s * HU + c4);
        const float2 fa = __half22float2(hv.a);
        const float2 fb = __half22float2(hv.b);
        d += w;
        acc.x += w * fa.x;
        acc.y += w * fa.y;
        acc.z += w * fb.x;
        acc.w += w * fb.y;
    }

    const float inv = 1.f / (d + EPSV);
    const float4 b = *reinterpret_cast<const float4*>(bias + c4);
    float v;
    float4 o;
    v = acc.x * inv + b.x; o.x = (v > 0.f) ? v : expm1f(v);
    v = acc.y * inv + b.y; o.y = (v > 0.f) ? v : expm1f(v);
    v = acc.z * inv + b.z; o.z = (v > 0.f) ? v : expm1f(v);
    v = acc.w * inv + b.w; o.w = (v > 0.f) ? v : expm1f(v);
    *reinterpret_cast<float4*>(out + (size_t)n * HU + c4) = o;
}

extern "C" void kernel_launch(void* const* d_in, const int* in_sizes, int n_in,
                              void* d_out, int out_size, void* d_ws, size_t ws_size,
                              hipStream_t stream) {
    const float* x = (const float*)d_in[0];
    const int* edges = (const int*)d_in[1];
    const float* W = (const float*)d_in[2];
    const float* ka1 = (const float*)d_in[3];
    // d_in[4] = ka2: unused by the reference
    const float* bias = (const float*)d_in[5];
    float* out = (float*)d_out;

    char* ws = (char*)d_ws;
    size_t off = 0;
    auto alloc = [&](size_t bytes) -> void* {
        void* p = ws + off;
        off = (off + bytes + 255) & ~size_t(255);
        return p;
    };
    __half* h = (__half*)alloc(sizeof(__half) * (size_t)N_NODES * HU); // 25.6 MB
    __half* Wt = (__half*)alloc(sizeof(__half) * D_FEAT * HU);         // 64 KB
    float* f = (float*)alloc(sizeof(float) * N_NODES * HEADS);         // 1.6 MB
    float* g = (float*)alloc(sizeof(float) * N_NODES * HEADS);         // 1.6 MB
    int* counts = (int*)alloc(sizeof(int) * N_NODES);
    int* offs = (int*)alloc(sizeof(int) * N_NODES);
    int* gtotal = (int*)alloc(sizeof(int) * 64);
    int* rank = (int*)alloc(sizeof(int) * N_EDGES);                    // 3.2 MB
    int* elist = (int*)alloc(sizeof(int) * N_EDGES);                   // 3.2 MB

    k_wt<<<WBLK, 256, 0, stream>>>(W, Wt, counts, gtotal);
    k_big<<<GB + CB, 64, 0, stream>>>(x, Wt, ka1, edges, counts, rank, h, f);
    k_offs<<<NBLK, 256, 0, stream>>>(counts, edges, f, offs, g, gtotal);
    k_fill<<<EBLK, 256, 0, stream>>>(edges, offs, rank, elist);
    k_out<<<(N_NODES + 3) / 4, 256, 0, stream>>>(h, elist, f, g, offs, counts, bias, out);
}

// Round 25
// 140.562 us; speedup vs baseline: 1.0625x; 1.0625x over previous
//
#include <hip/hip_runtime.h>
#include <hip/hip_fp16.h>

#define N_NODES 50000
#define N_EDGES 800000
#define D_FEAT 128
#define HEADS 8
#define UNITS 32
#define HU (HEADS * UNITS) /* 256 */
#define LEAKY 0.2f
#define EPSV 1e-7f
#define NBLK 196 /* ceil(50000/256) */

typedef _Float16 half8 __attribute__((ext_vector_type(8)));
typedef float f32x4 __attribute__((ext_vector_type(4)));

struct h4pk { __half2 a, b; }; // 4 fp16 channels = 8 bytes

// ---- W -> W^T fp16 + zero counts ----
#define WBLK 128 /* 128*256 = 32768 = D_FEAT*HU */
__global__ __launch_bounds__(256) void k_wt(const float* __restrict__ W,
                                            __half* __restrict__ Wt,
                                            int* __restrict__ counts) {
    const int i = blockIdx.x * 256 + threadIdx.x; // i = n*128 + k
    const int n = i >> 7, k = i & 127;
    Wt[i] = __float2half(W[k * HU + n]);          // Wt[n][k] = W[k][n]
    for (int j = i; j < N_NODES; j += WBLK * 256) counts[j] = 0;
}

// ---- BIG: gemm blocks [0,GB) co-run with count/rank blocks [GB,GB+CB).
// gemm: 64-thread 2-tile MFMA, register-direct epilogue, (64,1) bounds.
#define GB 1563 /* ceil(50000/32) gemm blocks */
#define CB 3125 /* 800000/256 count blocks, 4 edges/thread */
__global__ __launch_bounds__(64, 1) void k_big(const float* __restrict__ x,
                                               const __half* __restrict__ Wt,
                                               const float* __restrict__ ka1,
                                               const int* __restrict__ edges,
                                               int* __restrict__ counts,
                                               int* __restrict__ rank,
                                               __half* __restrict__ h,
                                               float* __restrict__ f) {
    const int l = threadIdx.x;
    if (blockIdx.x >= GB) {
        const int base = (blockIdx.x - GB) * 256;
#pragma unroll
        for (int j = 0; j < 4; ++j) {
            const int e = base + j * 64 + l;
            if (e < N_EDGES) {
                const int tgt = edges[2 * e + 1];
                rank[e] = atomicAdd(&counts[tgt], 1);
            }
        }
        return;
    }
    const int row16 = l & 15, kg = l >> 4;
    const int rbase = blockIdx.x * 32;

    half8 a0[4], a1[4];
    const int r0 = min(rbase + row16, N_NODES - 1);
    const int r1 = min(rbase + 16 + row16, N_NODES - 1);
    const float* xp0 = x + (size_t)r0 * D_FEAT + kg * 8;
    const float* xp1 = x + (size_t)r1 * D_FEAT + kg * 8;
#pragma unroll
    for (int ks = 0; ks < 4; ++ks) {
        const float4 u0 = *reinterpret_cast<const float4*>(xp0 + ks * 32);
        const float4 v0 = *reinterpret_cast<const float4*>(xp0 + ks * 32 + 4);
        const float4 u1 = *reinterpret_cast<const float4*>(xp1 + ks * 32);
        const float4 v1 = *reinterpret_cast<const float4*>(xp1 + ks * 32 + 4);
        half8 t0, t1;
        t0[0] = (_Float16)u0.x; t0[1] = (_Float16)u0.y; t0[2] = (_Float16)u0.z; t0[3] = (_Float16)u0.w;
        t0[4] = (_Float16)v0.x; t0[5] = (_Float16)v0.y; t0[6] = (_Float16)v0.z; t0[7] = (_Float16)v0.w;
        t1[0] = (_Float16)u1.x; t1[1] = (_Float16)u1.y; t1[2] = (_Float16)u1.z; t1[3] = (_Float16)u1.w;
        t1[4] = (_Float16)v1.x; t1[5] = (_Float16)v1.y; t1[6] = (_Float16)v1.z; t1[7] = (_Float16)v1.w;
        a0[ks] = t0; a1[ks] = t1;
    }

    f32x4 acc0[16], acc1[16];
#pragma unroll
    for (int ct = 0; ct < 16; ++ct) {
        acc0[ct] = (f32x4){0.f, 0.f, 0.f, 0.f};
        acc1[ct] = (f32x4){0.f, 0.f, 0.f, 0.f};
    }

#pragma unroll
    for (int ct = 0; ct < 16; ++ct) {
        const __half* wp = Wt + (ct * 16 + row16) * D_FEAT + kg * 8;
#pragma unroll
        for (int ks = 0; ks < 4; ++ks) {
            const half8 bf = *reinterpret_cast<const half8*>(wp + ks * 32);
            acc0[ct] = __builtin_amdgcn_mfma_f32_16x16x32_f16(a0[ks], bf, acc0[ct], 0, 0, 0);
            acc1[ct] = __builtin_amdgcn_mfma_f32_16x16x32_f16(a1[ks], bf, acc1[ct], 0, 0, 0);
        }
    }

    // register-direct epilogue: scalar h stores from acc + shuffle-f
#pragma unroll
    for (int tile = 0; tile < 2; ++tile) {
        const int rb2 = rbase + tile * 16;
#pragma unroll
        for (int ct = 0; ct < 16; ++ct) {
            const int col = ct * 16 + row16;
            const f32x4 av = tile ? acc1[ct] : acc0[ct];
#pragma unroll
            for (int r = 0; r < 4; ++r) {
                const int hr = rb2 + kg * 4 + r;
                if (hr < N_NODES)
                    h[(size_t)hr * HU + col] = __float2half(av[r]);
            }
        }
#pragma unroll
        for (int hd = 0; hd < 8; ++hd) {
            const float ka = ka1[hd * 32 + row16];
            const float kb = ka1[hd * 32 + 16 + row16];
            const f32x4 ae = tile ? acc1[2 * hd] : acc0[2 * hd];
            const f32x4 ao = tile ? acc1[2 * hd + 1] : acc0[2 * hd + 1];
#pragma unroll
            for (int r = 0; r < 4; ++r) {
                float v = ae[r] * ka + ao[r] * kb;
                v += __shfl_xor(v, 1);
                v += __shfl_xor(v, 2);
                v += __shfl_xor(v, 4);
                v += __shfl_xor(v, 8);
                if (row16 == 0) {
                    const int hr = rb2 + kg * 4 + r;
                    if (hr < N_NODES) f[(size_t)hr * HEADS + hd] = v;
                }
            }
        }
    }
}

// ---- scanA: per-block totals of counts ----
__global__ __launch_bounds__(256) void k_scanA(const int* __restrict__ counts,
                                               int* __restrict__ partials) {
    const int i = blockIdx.x * 256 + threadIdx.x;
    int v = (i < N_NODES) ? counts[i] : 0;
#pragma unroll
    for (int m = 32; m >= 1; m >>= 1) v += __shfl_xor(v, m);
    __shared__ int ws[4];
    if ((threadIdx.x & 63) == 0) ws[threadIdx.x >> 6] = v;
    __syncthreads();
    if (threadIdx.x == 0) partials[blockIdx.x] = ws[0] + ws[1] + ws[2] + ws[3];
}

// ---- scanC: folds scanB + per-node exclusive scan + g-gather ----
__global__ __launch_bounds__(256) void k_scanC(const int* __restrict__ counts,
                                               const int* __restrict__ partials,
                                               const int* __restrict__ edges,
                                               const float* __restrict__ f,
                                               int* __restrict__ offs,
                                               float* __restrict__ g) {
    __shared__ int sp[256];
    __shared__ int s[256];
    const int t = threadIdx.x;

    sp[t] = (t < NBLK) ? partials[t] : 0;
    __syncthreads();
    for (int o = 1; o < 256; o <<= 1) {
        const int u = (t >= o) ? sp[t - o] : 0;
        __syncthreads();
        sp[t] += u;
        __syncthreads();
    }
    const int prefix = (blockIdx.x > 0) ? sp[blockIdx.x - 1] : 0;

    const int i = blockIdx.x * 256 + t;
    const int v = (i < N_NODES) ? counts[i] : 0;
    s[t] = v;
    __syncthreads();
    for (int o = 1; o < 256; o <<= 1) {
        const int u = (t >= o) ? s[t - o] : 0;
        __syncthreads();
        s[t] += u;
        __syncthreads();
    }
    if (i < N_NODES) {
        offs[i] = prefix + s[t] - v; // exclusive start
        const int t2 = edges[2 * i + 1]; // quirk: f_s = f_t[sources]
        const float4 A = *reinterpret_cast<const float4*>(f + (size_t)t2 * HEADS);
        const float4 B = *reinterpret_cast<const float4*>(f + (size_t)t2 * HEADS + 4);
        *reinterpret_cast<float4*>(g + (size_t)i * HEADS) = A;
        *reinterpret_cast<float4*>(g + (size_t)i * HEADS + 4) = B;
    }
}

// ---- atomic-free single-pass CSR fill ----
#define EBLK 3125 /* 3125*256 = 800,000 */
__global__ __launch_bounds__(256) void k_fill(const int* __restrict__ edges,
                                              const int* __restrict__ offs,
                                              const int* __restrict__ rank,
                                              int* __restrict__ elist) {
    const int e = blockIdx.x * 256 + threadIdx.x;
    if (e >= N_EDGES) return;
    const int2 st = reinterpret_cast<const int2*>(edges)[e];
    elist[offs[st.y] + rank[e]] = st.x;
}

// ---- single sweep, no-max softmax + weighted gather; 8-edge pipeline ----
__global__ __launch_bounds__(256) void k_out(const __half* __restrict__ h,
                                             const int* __restrict__ elist,
                                             const float* __restrict__ f,
                                             const float* __restrict__ g,
                                             const int* __restrict__ offs, // segment START
                                             const int* __restrict__ counts,
                                             const float* __restrict__ bias,
                                             float* __restrict__ out) {
    const int n = blockIdx.x * 4 + (threadIdx.x >> 6);
    if (n >= N_NODES) return;
    const int lane = threadIdx.x & 63;
    const int head = lane >> 3;
    const int c4 = lane * 4;
    const int start = offs[n];
    const int end = start + counts[n];
    const float fn = f[(size_t)n * HEADS + head];

    float d = 0.f;
    float4 acc = make_float4(0.f, 0.f, 0.f, 0.f);

    int p = start;
    for (; p + 8 <= end; p += 8) {
        int ss[8];
#pragma unroll
        for (int j = 0; j < 8; ++j) ss[j] = elist[p + j];
        float gz[8];
#pragma unroll
        for (int j = 0; j < 8; ++j) gz[j] = g[(size_t)ss[j] * HEADS + head];
        h4pk hv[8];
#pragma unroll
        for (int j = 0; j < 8; ++j) hv[j] = *reinterpret_cast<const h4pk*>(h + (size_t)ss[j] * HU + c4);
#pragma unroll
        for (int j = 0; j < 8; ++j) {
            float z = fn + gz[j];
            z = (z > 0.f) ? z : LEAKY * z;
            const float w = __expf(z);
            d += w;
            const float2 fa = __half22float2(hv[j].a);
            const float2 fb = __half22float2(hv[j].b);
            acc.x += w * fa.x; acc.y += w * fa.y; acc.z += w * fb.x; acc.w += w * fb.y;
        }
    }
    for (; p + 4 <= end; p += 4) {
        int ss[4];
#pragma unroll
        for (int j = 0; j < 4; ++j) ss[j] = elist[p + j];
        float gz[4];
#pragma unroll
        for (int j = 0; j < 4; ++j) gz[j] = g[(size_t)ss[j] * HEADS + head];
        h4pk hv[4];
#pragma unroll
        for (int j = 0; j < 4; ++j) hv[j] = *reinterpret_cast<const h4pk*>(h + (size_t)ss[j] * HU + c4);
#pragma unroll
        for (int j = 0; j < 4; ++j) {
            float z = fn + gz[j];
            z = (z > 0.f) ? z : LEAKY * z;
            const float w = __expf(z);
            d += w;
            const float2 fa = __half22float2(hv[j].a);
            const float2 fb = __half22float2(hv[j].b);
            acc.x += w * fa.x; acc.y += w * fa.y; acc.z += w * fb.x; acc.w += w * fb.y;
        }
    }
    for (; p < end; ++p) {
        const int s = elist[p];
        float z = fn + g[(size_t)s * HEADS + head];
        z = (z > 0.f) ? z : LEAKY * z;
        const float w = __expf(z);
        const h4pk hv = *reinterpret_cast<const h4pk*>(h + (size_t)s * HU + c4);
        const float2 fa = __half22float2(hv.a);
        const float2 fb = __half22float2(hv.b);
        d += w;
        acc.x += w * fa.x;
        acc.y += w * fa.y;
        acc.z += w * fb.x;
        acc.w += w * fb.y;
    }

    const float inv = 1.f / (d + EPSV);
    const float4 b = *reinterpret_cast<const float4*>(bias + c4);
    float v;
    float4 o;
    v = acc.x * inv + b.x; o.x = (v > 0.f) ? v : expm1f(v);
    v = acc.y * inv + b.y; o.y = (v > 0.f) ? v : expm1f(v);
    v = acc.z * inv + b.z; o.z = (v > 0.f) ? v : expm1f(v);
    v = acc.w * inv + b.w; o.w = (v > 0.f) ? v : expm1f(v);
    *reinterpret_cast<float4*>(out + (size_t)n * HU + c4) = o;
}

extern "C" void kernel_launch(void* const* d_in, const int* in_sizes, int n_in,
                              void* d_out, int out_size, void* d_ws, size_t ws_size,
                              hipStream_t stream) {
    const float* x = (const float*)d_in[0];
    const int* edges = (const int*)d_in[1];
    const float* W = (const float*)d_in[2];
    const float* ka1 = (const float*)d_in[3];
    // d_in[4] = ka2: unused by the reference
    const float* bias = (const float*)d_in[5];
    float* out = (float*)d_out;

    char* ws = (char*)d_ws;
    size_t off = 0;
    auto alloc = [&](size_t bytes) -> void* {
        void* p = ws + off;
        off = (off + bytes + 255) & ~size_t(255);
        return p;
    };
    __half* h = (__half*)alloc(sizeof(__half) * (size_t)N_NODES * HU); // 25.6 MB
    __half* Wt = (__half*)alloc(sizeof(__half) * D_FEAT * HU);         // 64 KB
    float* f = (float*)alloc(sizeof(float) * N_NODES * HEADS);         // 1.6 MB
    float* g = (float*)alloc(sizeof(float) * N_NODES * HEADS);         // 1.6 MB
    int* counts = (int*)alloc(sizeof(int) * N_NODES);
    int* offs = (int*)alloc(sizeof(int) * N_NODES);
    int* partials = (int*)alloc(sizeof(int) * NBLK);
    int* rank = (int*)alloc(sizeof(int) * N_EDGES);                    // 3.2 MB
    int* elist = (int*)alloc(sizeof(int) * N_EDGES);                   // 3.2 MB

    k_wt<<<WBLK, 256, 0, stream>>>(W, Wt, counts);
    k_big<<<GB + CB, 64, 0, stream>>>(x, Wt, ka1, edges, counts, rank, h, f);
    k_scanA<<<NBLK, 256, 0, stream>>>(counts, partials);
    k_scanC<<<NBLK, 256, 0, stream>>>(counts, partials, edges, f, offs, g);
    k_fill<<<EBLK, 256, 0, stream>>>(edges, offs, rank, elist);
    k_out<<<(N_NODES + 3) / 4, 256, 0, stream>>>(h, elist, f, g, offs, counts, bias, out);
}